// Round 7
// baseline (548.492 us; speedup 1.0000x reference)
//
#include <hip/hip_runtime.h>

// HiLoAttention on MI355X — round 9 (resubmit after infra failure):
// low_attn softmax VALU trim. sigma-interleaved P/V k-order (cvt_pk_bf16
// pair-writes, exact: PV contracts over k so a shared permutation is
// identity), exp2 fold, T14 async staging (next-phase global loads issued
// under current compute). B=8, DIM=256, H=W=96, WS=4.

#define SCALE_F 0.17677669529663687f   // 32^-0.5
#define SCALE_L2E 0.2550349f           // 32^-0.5 * log2(e)

typedef unsigned short u16;
typedef __attribute__((ext_vector_type(8))) short bf16x8;
typedef __attribute__((ext_vector_type(4))) float f32x4;
typedef __attribute__((ext_vector_type(8))) u16 u16x8;
typedef __attribute__((ext_vector_type(4))) u16 u16x4;

static __device__ __forceinline__ u16 f2bf(float f) {
    unsigned u = __float_as_uint(f);
    return (u16)((u + 0x7FFF + ((u >> 16) & 1)) >> 16);   // RNE
}
static __device__ __forceinline__ float bf2f(u16 v) {
    return __uint_as_float((unsigned)v << 16);
}
static __device__ __forceinline__ float ldf(float v) { return v; }
static __device__ __forceinline__ float ldf(u16 v)   { return bf2f(v); }

// ------------------------------------------------------------------ pool ----
__global__ __launch_bounds__(256) void pool_kernel(const float* __restrict__ x,
                                                   float* __restrict__ low) {
    int o = blockIdx.x * 256 + threadIdx.x;        // [b*256+c][hg][wg]
    int wg = o % 24;
    int t  = o / 24;
    int hg = t % 24;
    int bc = t / 24;
    const float* xp = x + (size_t)bc * 9216 + (hg * 4) * 96 + wg * 4;
    float s = 0.f;
#pragma unroll
    for (int r = 0; r < 4; r++) {
        float4 v = *(const float4*)(xp + r * 96);
        s += (v.x + v.y) + (v.z + v.w);
    }
    low[o] = s * (1.f / 16.f);
}

// ------------- high = restore(pixshuf(low)) - x, bf16 out, reg-reuse --------
__global__ __launch_bounds__(256) void high_kernel(const float* __restrict__ x,
                                                   const float* __restrict__ low,
                                                   const float* __restrict__ rw,
                                                   const float* __restrict__ rb,
                                                   u16* __restrict__ high) {
    int px = blockIdx.x * 256 + threadIdx.x;       // 0..9215
    int cg = blockIdx.y;                           // channel chunk (64 each)
    int b  = blockIdx.z;
    int h = px / 96, w = px % 96;
    int sub = (h & 3) * 4 + (w & 3);               // pixel-shuffle sub-channel
    const float* lp = low + ((size_t)b * 256 + sub) * 576 + (h >> 2) * 24 + (w >> 2);
    float lv[16];
#pragma unroll
    for (int co = 0; co < 16; co++) lv[co] = lp[(size_t)co * 16 * 576];
    const float* xp = x    + ((size_t)b * 256 + cg * 64) * 9216 + px;
    u16*         hp = high + ((size_t)b * 256 + cg * 64) * 9216 + px;
#pragma unroll 4
    for (int cl = 0; cl < 64; cl++) {
        int c = cg * 64 + cl;                      // uniform -> rw/rb scalar loads
        float a = rb[c] - xp[(size_t)cl * 9216];
#pragma unroll
        for (int co = 0; co < 16; co++)
            a = fmaf(rw[c * 16 + co], lv[co], a);
        hp[(size_t)cl * 9216] = f2bf(a);
    }
}

// ------------------------- pw-weight fp32 -> bf16 conversion ----------------
__global__ __launch_bounds__(256) void wcvt_kernel(const float* __restrict__ s0,
                                                   const float* __restrict__ s1,
                                                   const float* __restrict__ s2,
                                                   const float* __restrict__ s3,
                                                   const float* __restrict__ s4,
                                                   u16* __restrict__ W) {
    int i = blockIdx.x * 256 + threadIdx.x;        // 229376 total
    float v;
    if      (i < 32768)  v = s0[i];
    else if (i < 98304)  v = s1[i - 32768];
    else if (i < 114688) v = s2[i - 98304];
    else if (i < 212992) v = s3[i - 114688];
    else                 v = s4[i - 212992];
    W[i] = f2bf(v);
}

// ------ depthwise 3x3 -> bf16 k-interleaved Y [b][C/8][HW][8], strip/thread --
// Thread = 1 channel x 8-px horizontal strip (strips never cross rows).
// 3 vector row-loads + 6 halo scalars per 8 outputs; taps in reference order.
template <int C, int IMH, int IMW, typename TIN>
__global__ __launch_bounds__(256) void dw_kernel(const TIN* __restrict__ in,
                                                 const float* __restrict__ dww,
                                                 const float* __restrict__ dwb,
                                                 u16* __restrict__ Y) {
    constexpr int HW = IMH * IMW;
    constexpr int NSTRIP = HW / 8;
    const int strip = blockIdx.x * 32 + (threadIdx.x >> 3);
    if (strip >= NSTRIP) return;
    const int icq = threadIdx.x & 7;
    const int icg = blockIdx.y, b = blockIdx.z;
    const int ic  = icg * 8 + icq;
    const int px0 = strip * 8;
    const int h   = px0 / IMW, w0 = px0 % IMW;

    const TIN* ip = in + ((size_t)b * C + ic) * HW;
    float r[3][8], lh[3], rh[3];
#pragma unroll
    for (int dr = 0; dr < 3; dr++) {
        int hh = h + dr - 1;
        if (hh < 0 || hh >= IMH) {
#pragma unroll
            for (int j = 0; j < 8; j++) r[dr][j] = 0.f;
            lh[dr] = 0.f; rh[dr] = 0.f;
        } else {
            const TIN* rp = ip + hh * IMW + w0;
            if constexpr (sizeof(TIN) == 4) {
                float4 a = *(const float4*)rp;
                float4 c = *(const float4*)(rp + 4);
                r[dr][0] = a.x; r[dr][1] = a.y; r[dr][2] = a.z; r[dr][3] = a.w;
                r[dr][4] = c.x; r[dr][5] = c.y; r[dr][6] = c.z; r[dr][7] = c.w;
            } else {
                u16x8 a = *(const u16x8*)rp;
#pragma unroll
                for (int j = 0; j < 8; j++) r[dr][j] = bf2f(a[j]);
            }
            lh[dr] = (w0 > 0)           ? ldf(rp[-1]) : 0.f;
            rh[dr] = (w0 + 8 < IMW)     ? ldf(rp[8])  : 0.f;
        }
    }
    const float* wp = dww + ic * 9;
    float wv[9];
#pragma unroll
    for (int t = 0; t < 9; t++) wv[t] = wp[t];
    const float b0 = dwb[ic];

    u16* op = Y + (((size_t)b * (C / 8) + icg) * HW + px0) * 8 + icq;
#pragma unroll
    for (int j = 0; j < 8; j++) {
        float y = b0;
#pragma unroll
        for (int dr = 0; dr < 3; dr++) {
            float l = (j == 0) ? lh[dr] : r[dr][j - 1];
            float m = r[dr][j];
            float rr = (j == 7) ? rh[dr] : r[dr][j + 1];
            y = fmaf(wv[dr * 3 + 0], l, y);
            y = fmaf(wv[dr * 3 + 1], m, y);
            y = fmaf(wv[dr * 3 + 2], rr, y);
        }
        op[j * 8] = f2bf(y);
    }
}

// --------------- pointwise 1x1 as bf16 MFMA GEMM: out = W x Y + bias --------
// MODE 0: out[b][totc][M] (TOUT). MODE 1 (hqkv): window-major dual layout:
//   oc<256 (Q,K): qkout[((b*576+g)*16+q)*256 + oc]          (q-major)
//   oc>=256 (V):  vout[((b*576+g)*128 + oc-256)*16 + q]     (ch-major)
// MODE 1 epilogue restages acc through LDS so global stores are wide and
// line-coalesced (fix for 4.7x HBM write amplification of 2B scatter).
template <int IC, int M, typename TOUT, int MODE>
__global__ __launch_bounds__(256) void pw_gemm(const u16* __restrict__ Y,
                                               const u16* __restrict__ Wmat,
                                               const float* __restrict__ bias,
                                               TOUT* __restrict__ out,
                                               int totc, int ocoff,
                                               u16* __restrict__ qkout,
                                               u16* __restrict__ vout) {
    const int tid  = threadIdx.x;
    const int wave = tid >> 6, lane = tid & 63;
    const int col  = lane & 15, oct = lane >> 4;
    const int mw   = (wave & 1) * 64, nw = (wave >> 1) * 64;
    const int px0    = blockIdx.x * 128;
    const int octile = blockIdx.y;
    const int b      = blockIdx.z;

    __shared__ union {
        struct { u16 W[128 * 72]; u16 Y[8 * 128 * 8]; } g;   // 34816 B
        u16 stage[4][64 * 72];                               // 36864 B (MODE 1)
    } lds;
    u16* const Wlds = lds.g.W;      // [oc][64ic] rows padded 64->72
    u16* const Ylds = lds.g.Y;      // [icg][px][8]

    f32x4 acc[4][4];
    const f32x4 zero = {0.f, 0.f, 0.f, 0.f};
#pragma unroll
    for (int i = 0; i < 4; i++)
#pragma unroll
        for (int j = 0; j < 4; j++) acc[i][j] = zero;

    const u16* Yb = Y + (size_t)b * (IC / 8) * M * 8;

    for (int kc = 0; kc < IC; kc += 64) {
        __syncthreads();
#pragma unroll
        for (int i = 0; i < 4; i++) {              // stage W tile (16 KB)
            int c = tid + i * 256;
            int r = c >> 3, seg = c & 7;
            u16x8 v = *(const u16x8*)(Wmat + (size_t)(octile * 128 + r) * IC + kc + seg * 8);
            *(u16x8*)&Wlds[r * 72 + seg * 8] = v;
        }
#pragma unroll
        for (int i = 0; i < 4; i++) {              // stage Y tile (16 KB)
            int c = tid + i * 256;
            int ig = c >> 7, pl = c & 127;
            int px = px0 + pl; if (px > M - 1) px = M - 1;   // clamp partial tile
            u16x8 v = *(const u16x8*)(Yb + ((size_t)(kc / 8 + ig) * M + px) * 8);
            *(u16x8*)&Ylds[(ig * 128 + pl) * 8] = v;
        }
        __syncthreads();
#pragma unroll
        for (int kcs = 0; kcs < 2; kcs++) {
            bf16x8 Af[4], Bf[4];
#pragma unroll
            for (int mt = 0; mt < 4; mt++)         // A[m=oc][k=ic]
                Af[mt] = *(const bf16x8*)&Wlds[(mw + mt * 16 + col) * 72 + kcs * 32 + oct * 8];
#pragma unroll
            for (int nt = 0; nt < 4; nt++)         // B[k=ic][n=px]
                Bf[nt] = *(const bf16x8*)&Ylds[((kcs * 4 + oct) * 128 + nw + nt * 16 + col) * 8];
#pragma unroll
            for (int mt = 0; mt < 4; mt++)
#pragma unroll
                for (int nt = 0; nt < 4; nt++)
                    acc[mt][nt] = __builtin_amdgcn_mfma_f32_16x16x32_bf16(
                        Af[mt], Bf[nt], acc[mt][nt], 0, 0, 0);
        }
    }
    if constexpr (MODE == 1) {
        // ---- restage wave's 64(oc) x 64(px) tile to LDS as [px][oc] (pad 72)
        __syncthreads();                           // all waves done with W/Y LDS
        u16* const stg = lds.stage[wave];
#pragma unroll
        for (int mt = 0; mt < 4; mt++)
#pragma unroll
            for (int nt = 0; nt < 4; nt++) {
                u16x4 pk;
#pragma unroll
                for (int i = 0; i < 4; i++) {
                    int oc = octile * 128 + mw + mt * 16 + oct * 4 + i;
                    pk[i] = f2bf(acc[mt][nt][i] + bias[oc]);
                }
                *(u16x4*)&stg[(nt * 16 + col) * 72 + mt * 16 + oct * 4] = pk;
            }
        __syncthreads();
        if (octile < 2) {
            // QK: per (g,q) row the wave owns a contiguous 128B oc-chunk.
            // 4 lanes/px x u16x8 -> each store instr covers 16 full 64B lines.
            const int p4 = lane >> 2, piece = lane & 3;
#pragma unroll
            for (int pp = 0; pp < 4; pp++) {
                int pl = pp * 16 + p4;             // px_local 0..63
                int px = px0 + nw + pl;
                int h = px / 96, w = px - h * 96;
                int g = (h >> 2) * 24 + (w >> 2);
                int q = (h & 3) * 4 + (w & 3);
                size_t base = (((size_t)b * 576 + g) * 16 + q) * 256
                            + (size_t)(octile * 128 + mw);
#pragma unroll
                for (int half = 0; half < 2; half++) {
                    u16x8 v = *(const u16x8*)&stg[pl * 72 + half * 32 + piece * 8];
                    *(u16x8*)&qkout[base + half * 32 + piece * 8] = v;
                }
            }
        } else {
            // V (ch-major): pack the 4 consecutive q of a window row into one
            // 8B store; lanes sweep consecutive vc. Adjacent bx blocks supply
            // the other q-rows of the same lines (L2 merge).
#pragma unroll
            for (int it = 0; it < 16; it++) {
                int pl0 = it * 4;                  // 4-px run, same (g, qrow)
                int px = px0 + nw + pl0;
                int h = px / 96, w = px - h * 96;
                int g = (h >> 2) * 24 + (w >> 2);
                int qrow = h & 3;
                int vc = mw + lane;
                u16x4 pk;
#pragma unroll
                for (int j = 0; j < 4; j++) pk[j] = stg[(pl0 + j) * 72 + lane];
                *(u16x4*)&vout[(((size_t)b * 576 + g) * 128 + vc) * 16 + qrow * 4] = pk;
            }
        }
        return;
    }
    // MODE 0 epilogue: C row = oc (oct*4+i), col = px (lane&15)
#pragma unroll
    for (int mt = 0; mt < 4; mt++) {
#pragma unroll
        for (int i = 0; i < 4; i++) {
            int ocl = mw + mt * 16 + oct * 4 + i;
            int oc  = octile * 128 + ocl;
            float bv = bias[oc];
            TOUT* op = out + ((size_t)b * totc + ocoff + oc) * M;
#pragma unroll
            for (int nt = 0; nt < 4; nt++) {
                int px = px0 + nw + nt * 16 + col;
                if (px < M) {
                    float v = acc[mt][nt][i] + bv;
                    if constexpr (sizeof(TOUT) == 2) op[px] = (TOUT)f2bf(v);
                    else                             op[px] = v;
                }
            }
        }
    }
}

// ------------------- low (global) attention — bf16 MFMA, tiled --------------
// 6 phases of 96 keys; T14 async staging (next-phase loads under compute).
// P and V share a sigma-permuted k-order within each 32-block
// (s even -> k=s/2, s odd -> k=16+s/2): exact since PV contracts over k.
// Lane's P pair (k=col, k=col+16) -> one v_cvt_pk_bf16_f32 + one b32 write.
// LDS: K 96x56 + V 32x104 + P 4x16x40 = 22528 B.
__global__ __launch_bounds__(256) void low_attn_mfma(const u16* __restrict__ lq,
                                                     const u16* __restrict__ lkv,
                                                     u16* __restrict__ o) {
    const int qtile = blockIdx.x, head = blockIdx.y, b = blockIdx.z;
    const int tid  = threadIdx.x;
    const int wave = tid >> 6, lane = tid & 63;
    const int col  = lane & 15, oct = lane >> 4;

    __shared__ u16 Klds[96][56];    // [k][d] transposed K, d padded 32->56
    __shared__ u16 Vlds[32][104];   // [d][sigma(k)], k padded 96->104
    __shared__ u16 Plds[4][16][40]; // [wave][q][sigma(k) 32, pad->40 (16B rows)]

    const size_t qb  = ((size_t)b * 128 + head * 32) * 9216;
    const size_t kb  = ((size_t)b * 256 + head * 32) * 576;
    const size_t vb  = kb + (size_t)128 * 576;
    const int    q0w = qtile * 256 + wave * 64;

    // staging geometry (phase-invariant): 768 = 32d x 24 groups of 4 keys
    int sd[3], skq[3], sv0[3];
#pragma unroll
    for (int i = 0; i < 3; i++) {
        int idx = tid + i * 256;
        sd[i]  = idx / 24;
        skq[i] = (idx % 24) * 4;
        int r  = skq[i] & 31;
        sv0[i] = (skq[i] >> 5) * 32 + ((r & 15) << 1) + (r >> 4);  // sigma dst
    }

    bf16x8 Qf[4];                                   // A[m=q][k=d]
#pragma unroll
    for (int qt = 0; qt < 4; qt++)
#pragma unroll
        for (int j = 0; j < 8; j++)
            Qf[qt][j] = (short)lq[qb + (size_t)(oct * 8 + j) * 9216 + q0w + qt * 16 + col];

    bf16x8 ones;
#pragma unroll
    for (int j = 0; j < 8; j++) ones[j] = (short)0x3F80;

    f32x4 Oacc[4][2], Lacc[4];
    const f32x4 zero = {0.f, 0.f, 0.f, 0.f};
#pragma unroll
    for (int qt = 0; qt < 4; qt++) {
        Oacc[qt][0] = zero; Oacc[qt][1] = zero; Lacc[qt] = zero;
    }

    u16x4 kr[3], vr[3];                             // prologue: phase-0 loads
#pragma unroll
    for (int i = 0; i < 3; i++) {
        kr[i] = *(const u16x4*)(lkv + kb + (size_t)sd[i] * 576 + skq[i]);
        vr[i] = *(const u16x4*)(lkv + vb + (size_t)sd[i] * 576 + skq[i]);
    }

    for (int ph = 0; ph < 6; ph++) {
        __syncthreads();                            // prior compute done
#pragma unroll
        for (int i = 0; i < 3; i++) {               // write staged regs to LDS
            Klds[skq[i] + 0][sd[i]] = kr[i].x;
            Klds[skq[i] + 1][sd[i]] = kr[i].y;
            Klds[skq[i] + 2][sd[i]] = kr[i].z;
            Klds[skq[i] + 3][sd[i]] = kr[i].w;
            u16* vp = &Vlds[sd[i]][0];              // sigma: stride-2 u16
            vp[sv0[i] + 0] = vr[i].x;
            vp[sv0[i] + 2] = vr[i].y;
            vp[sv0[i] + 4] = vr[i].z;
            vp[sv0[i] + 6] = vr[i].w;
        }
        __syncthreads();
        if (ph < 5) {                               // issue next-phase loads
            const int k0 = (ph + 1) * 96;
#pragma unroll
            for (int i = 0; i < 3; i++) {
                kr[i] = *(const u16x4*)(lkv + kb + (size_t)sd[i] * 576 + k0 + skq[i]);
                vr[i] = *(const u16x4*)(lkv + vb + (size_t)sd[i] * 576 + k0 + skq[i]);
            }
        }

        for (int kc = 0; kc < 96; kc += 32) {
            bf16x8 Kf0 = *(const bf16x8*)&Klds[kc + col][oct * 8];
            bf16x8 Kf1 = *(const bf16x8*)&Klds[kc + 16 + col][oct * 8];
            bf16x8 Vf0 = *(const bf16x8*)&Vlds[col][kc + oct * 8];
            bf16x8 Vf1 = *(const bf16x8*)&Vlds[16 + col][kc + oct * 8];
#pragma unroll
            for (int qt = 0; qt < 4; qt++) {
                f32x4 S0 = __builtin_amdgcn_mfma_f32_16x16x32_bf16(Qf[qt], Kf0, zero, 0, 0, 0);
                f32x4 S1 = __builtin_amdgcn_mfma_f32_16x16x32_bf16(Qf[qt], Kf1, zero, 0, 0, 0);
#pragma unroll
                for (int i = 0; i < 4; i++) {       // P pair (k=col, k=col+16)
                    float e0 = exp2f(S0[i] * SCALE_L2E);
                    float e1 = exp2f(S1[i] * SCALE_L2E);
                    unsigned pk;
                    asm("v_cvt_pk_bf16_f32 %0, %1, %2" : "=v"(pk) : "v"(e0), "v"(e1));
                    ((unsigned*)&Plds[wave][oct * 4 + i][0])[col] = pk;
                }
                bf16x8 Pf = *(const bf16x8*)&Plds[wave][col][oct * 8];
                Oacc[qt][0] = __builtin_amdgcn_mfma_f32_16x16x32_bf16(Pf, Vf0, Oacc[qt][0], 0, 0, 0);
                Oacc[qt][1] = __builtin_amdgcn_mfma_f32_16x16x32_bf16(Pf, Vf1, Oacc[qt][1], 0, 0, 0);
                Lacc[qt]    = __builtin_amdgcn_mfma_f32_16x16x32_bf16(Pf, ones, Lacc[qt], 0, 0, 0);
            }
        }
    }

#pragma unroll
    for (int qt = 0; qt < 4; qt++) {
        f32x4 rl;
#pragma unroll
        for (int i = 0; i < 4; i++) rl[i] = 1.f / Lacc[qt][i];
#pragma unroll
        for (int dh = 0; dh < 2; dh++)
#pragma unroll
            for (int i = 0; i < 4; i++)
                o[qb + (size_t)(dh * 16 + col) * 9216 + q0w + qt * 16 + oct * 4 + i] =
                    f2bf(Oacc[qt][dh][i] * rl[i]);
    }
}

// ----------- high (windowed 4x4) attention — MFMA, direct global ------------
__global__ __launch_bounds__(256) void high_attn_mfma(const u16* __restrict__ qk,
                                                      const u16* __restrict__ v,
                                                      u16* __restrict__ ho) {
    const int wave = threadIdx.x >> 6, lane = threadIdx.x & 63;
    const int col = lane & 15, oct = lane >> 4;
    const int gidx = blockIdx.x * 4 + wave;        // 0..4607
    const int b = gidx / 576, g = gidx % 576;

    __shared__ u16 Plds[4][16][36];                // per-wave, keys padded to 32
    for (int i = lane; i < 16 * 20; i += 64) {     // zero key cols 16..35 once
        Plds[wave][i / 20][16 + i % 20] = 0;
    }
    const u16* qkw = qk + (size_t)gidx * 16 * 256;
    const u16* vw  = v  + (size_t)gidx * 128 * 16;
    const int px0  = ((g / 24) * 4) * 96 + (g % 24) * 4;
    u16* ob = ho + (size_t)b * 128 * 9216 + px0;
    const int qy = col >> 2, qx = col & 3;

    const f32x4 zero = {0.f, 0.f, 0.f, 0.f};
    bf16x8 ones;
#pragma unroll
    for (int j = 0; j < 8; j++) ones[j] = (short)0x3F80;

#pragma unroll
    for (int hd = 0; hd < 4; hd++) {
        bf16x8 Qf = *(const bf16x8*)(qkw + col * 256 + hd * 32 + oct * 8);
        bf16x8 Kf = *(const bf16x8*)(qkw + col * 256 + 128 + hd * 32 + oct * 8);
        f32x4 S = __builtin_amdgcn_mfma_f32_16x16x32_bf16(Qf, Kf, zero, 0, 0, 0);
#pragma unroll
        for (int i = 0; i < 4; i++)                // S[q=oct*4+i][key=col]
            Plds[wave][oct * 4 + i][col] = f2bf(__expf(S[i] * SCALE_F));
        bf16x8 Pf = *(const bf16x8*)&Plds[wave][col][oct * 8];
        bf16x8 Vf0 = *(const bf16x8*)(vw + (hd * 32 + col) * 16 + oct * 8);
        bf16x8 Vf1 = *(const bf16x8*)(vw + (hd * 32 + 16 + col) * 16 + oct * 8);
        f32x4 O0 = __builtin_amdgcn_mfma_f32_16x16x32_bf16(Vf0, Pf, zero, 0, 0, 0);
        f32x4 O1 = __builtin_amdgcn_mfma_f32_16x16x32_bf16(Vf1, Pf, zero, 0, 0, 0);
        f32x4 Ld = __builtin_amdgcn_mfma_f32_16x16x32_bf16(ones, Pf, zero, 0, 0, 0);
        float rl = 1.f / Ld[0];                    // L[q=col] (any row)
#pragma unroll
        for (int i = 0; i < 4; i++) {              // O[d][q=col]
            ob[(size_t)(hd * 32 + oct * 4 + i) * 9216 + qy * 96 + qx]      = f2bf(O0[i] * rl);
            ob[(size_t)(hd * 32 + 16 + oct * 4 + i) * 9216 + qy * 96 + qx] = f2bf(O1[i] * rl);
        }
    }
}

// ---------------------------------------------------------------- launch ----
extern "C" void kernel_launch(void* const* d_in, const int* in_sizes, int n_in,
                              void* d_out, int out_size, void* d_ws, size_t ws_size,
                              hipStream_t stream) {
    const float* x         = (const float*)d_in[0];
    const float* restore_w = (const float*)d_in[1];
    const float* restore_b = (const float*)d_in[2];
    const float* lq_dw_w   = (const float*)d_in[3];
    const float* lq_dw_b   = (const float*)d_in[4];
    const float* lq_pw_w   = (const float*)d_in[5];
    const float* lq_pw_b   = (const float*)d_in[6];
    const float* lkv_dw_w  = (const float*)d_in[7];
    const float* lkv_dw_b  = (const float*)d_in[8];
    const float* lkv_pw_w  = (const float*)d_in[9];
    const float* lkv_pw_b  = (const float*)d_in[10];
    const float* lpr_dw_w  = (const float*)d_in[11];
    const float* lpr_dw_b  = (const float*)d_in[12];
    const float* lpr_pw_w  = (const float*)d_in[13];
    const float* lpr_pw_b  = (const float*)d_in[14];
    const float* hq_dw_w   = (const float*)d_in[15];
    const float* hq_dw_b   = (const float*)d_in[16];
    const float* hq_pw_w   = (const float*)d_in[17];
    const float* hq_pw_b   = (const float*)d_in[18];
    const float* hp_dw_w   = (const float*)d_in[19];
    const float* hp_dw_b   = (const float*)d_in[20];
    const float* hp_pw_w   = (const float*)d_in[21];
    const float* hp_pw_b   = (const float*)d_in[22];
    float* out = (float*)d_out;
    char*  wsb = (char*)d_ws;

    // -------- workspace layout (bytes); all overlays safe by stream order ----
    u16*   Wbf    = (u16*)  (wsb + 0);           //  0.46 MB
    float* low    = (float*)(wsb + 524288);      //  4.7 MB fp32
    u16*   highbf = (u16*)  (wsb + 5242880);     // 18.9 MB bf16
    u16*   ho     = (u16*)  (wsb + 5242880);     // reuse (high dead after dw hqkv)
    u16*   Yhproj = (u16*)  (wsb + 24117248);    // 18.9 MB
    u16*   Ylq    = (u16*)  (wsb + 80740352);    // 37.7 MB
    u16*   Yhqkv  = (u16*)  (wsb + 80740352);    // reuse Ylq
    u16*   lqbf   = (u16*)  (wsb + 118489088);   // 18.9 MB
    u16*   QKwin  = (u16*)  (wsb + 118489088);   // 37.7 MB (overlays dead lqbf/attnL)
    u16*   Vwin   = (u16*)  (wsb + 156237824);   // 18.9 MB (overlays dead attnL/Ylproj)
    u16*   Ylkv   = (u16*)  (wsb + 137363456);   //  2.4 MB
    u16*   lkvbf  = (u16*)  (wsb + 139722752);   //  2.4 MB
    u16*   attnL  = (u16*)  (wsb + 142082048);   // 18.9 MB
    u16*   Ylproj = (u16*)  (wsb + 160956416);   // 18.9 MB -> peak 179.8 MB

    const u16* wlq    = Wbf;
    const u16* wlkv   = Wbf + 32768;
    const u16* wlproj = Wbf + 98304;
    const u16* whqkv  = Wbf + 114688;
    const u16* whproj = Wbf + 212992;

    wcvt_kernel<<<896, 256, 0, stream>>>(lq_pw_w, lkv_pw_w, lpr_pw_w, hq_pw_w, hp_pw_w, Wbf);
    pool_kernel<<<4608, 256, 0, stream>>>(x, low);
    high_kernel<<<dim3(36, 4, 8), 256, 0, stream>>>(x, low, restore_w, restore_b, highbf);

    dw_kernel<256, 96, 96, float><<<dim3(36, 32, 8), 256, 0, stream>>>(x, lq_dw_w, lq_dw_b, Ylq);
    pw_gemm<256, 9216, u16, 0><<<dim3(72, 1, 8), 256, 0, stream>>>(
        Ylq, wlq, lq_pw_b, lqbf, 128, 0, nullptr, nullptr);

    dw_kernel<256, 24, 24, float><<<dim3(3, 32, 8), 256, 0, stream>>>(low, lkv_dw_w, lkv_dw_b, Ylkv);
    pw_gemm<256, 576, u16, 0><<<dim3(5, 2, 8), 256, 0, stream>>>(
        Ylkv, wlkv, lkv_pw_b, lkvbf, 256, 0, nullptr, nullptr);

    low_attn_mfma<<<dim3(36, 4, 8), 256, 0, stream>>>(lqbf, lkvbf, attnL);

    dw_kernel<128, 96, 96, u16><<<dim3(36, 16, 8), 256, 0, stream>>>(attnL, lpr_dw_w, lpr_dw_b, Ylproj);
    pw_gemm<128, 9216, float, 0><<<dim3(72, 1, 8), 256, 0, stream>>>(
        Ylproj, wlproj, lpr_pw_b, out, 256, 0, nullptr, nullptr);

    dw_kernel<256, 96, 96, u16><<<dim3(36, 32, 8), 256, 0, stream>>>(highbf, hq_dw_w, hq_dw_b, Yhqkv);
    pw_gemm<256, 9216, u16, 1><<<dim3(72, 3, 8), 256, 0, stream>>>(
        Yhqkv, whqkv, hq_pw_b, QKwin, 384, 0, QKwin, Vwin);

    high_attn_mfma<<<1152, 256, 0, stream>>>(QKwin, Vwin, ho);

    dw_kernel<128, 96, 96, u16><<<dim3(36, 16, 8), 256, 0, stream>>>(ho, hp_dw_w, hp_dw_b, Yhproj);
    pw_gemm<128, 9216, float, 0><<<dim3(72, 1, 8), 256, 0, stream>>>(
        Yhproj, whproj, hp_pw_b, out, 256, 128, nullptr, nullptr);
}

// Round 8
// 537.660 us; speedup vs baseline: 1.0201x; 1.0201x over previous
//
#include <hip/hip_runtime.h>

// HiLoAttention on MI355X — round 10: revert r9 softmax bundle (regressed);
// low_attn back to r8 inner loop. Single change vs r8: split q-range per
// block 256->128 (qt=2), grid 36->72 qtiles => 2304 blocks = 9/CU to fix
// measured 23.8% occupancy (latency-bound, both pipes idle).
// B=8, DIM=256, H=W=96, WS=4.

#define SCALE_F 0.17677669529663687f   // 32^-0.5

typedef unsigned short u16;
typedef __attribute__((ext_vector_type(8))) short bf16x8;
typedef __attribute__((ext_vector_type(4))) float f32x4;
typedef __attribute__((ext_vector_type(8))) u16 u16x8;
typedef __attribute__((ext_vector_type(4))) u16 u16x4;

static __device__ __forceinline__ u16 f2bf(float f) {
    unsigned u = __float_as_uint(f);
    return (u16)((u + 0x7FFF + ((u >> 16) & 1)) >> 16);   // RNE
}
static __device__ __forceinline__ float bf2f(u16 v) {
    return __uint_as_float((unsigned)v << 16);
}
static __device__ __forceinline__ float ldf(float v) { return v; }
static __device__ __forceinline__ float ldf(u16 v)   { return bf2f(v); }

// ------------------------------------------------------------------ pool ----
__global__ __launch_bounds__(256) void pool_kernel(const float* __restrict__ x,
                                                   float* __restrict__ low) {
    int o = blockIdx.x * 256 + threadIdx.x;        // [b*256+c][hg][wg]
    int wg = o % 24;
    int t  = o / 24;
    int hg = t % 24;
    int bc = t / 24;
    const float* xp = x + (size_t)bc * 9216 + (hg * 4) * 96 + wg * 4;
    float s = 0.f;
#pragma unroll
    for (int r = 0; r < 4; r++) {
        float4 v = *(const float4*)(xp + r * 96);
        s += (v.x + v.y) + (v.z + v.w);
    }
    low[o] = s * (1.f / 16.f);
}

// ------------- high = restore(pixshuf(low)) - x, bf16 out, reg-reuse --------
__global__ __launch_bounds__(256) void high_kernel(const float* __restrict__ x,
                                                   const float* __restrict__ low,
                                                   const float* __restrict__ rw,
                                                   const float* __restrict__ rb,
                                                   u16* __restrict__ high) {
    int px = blockIdx.x * 256 + threadIdx.x;       // 0..9215
    int cg = blockIdx.y;                           // channel chunk (64 each)
    int b  = blockIdx.z;
    int h = px / 96, w = px % 96;
    int sub = (h & 3) * 4 + (w & 3);               // pixel-shuffle sub-channel
    const float* lp = low + ((size_t)b * 256 + sub) * 576 + (h >> 2) * 24 + (w >> 2);
    float lv[16];
#pragma unroll
    for (int co = 0; co < 16; co++) lv[co] = lp[(size_t)co * 16 * 576];
    const float* xp = x    + ((size_t)b * 256 + cg * 64) * 9216 + px;
    u16*         hp = high + ((size_t)b * 256 + cg * 64) * 9216 + px;
#pragma unroll 4
    for (int cl = 0; cl < 64; cl++) {
        int c = cg * 64 + cl;                      // uniform -> rw/rb scalar loads
        float a = rb[c] - xp[(size_t)cl * 9216];
#pragma unroll
        for (int co = 0; co < 16; co++)
            a = fmaf(rw[c * 16 + co], lv[co], a);
        hp[(size_t)cl * 9216] = f2bf(a);
    }
}

// ------------------------- pw-weight fp32 -> bf16 conversion ----------------
__global__ __launch_bounds__(256) void wcvt_kernel(const float* __restrict__ s0,
                                                   const float* __restrict__ s1,
                                                   const float* __restrict__ s2,
                                                   const float* __restrict__ s3,
                                                   const float* __restrict__ s4,
                                                   u16* __restrict__ W) {
    int i = blockIdx.x * 256 + threadIdx.x;        // 229376 total
    float v;
    if      (i < 32768)  v = s0[i];
    else if (i < 98304)  v = s1[i - 32768];
    else if (i < 114688) v = s2[i - 98304];
    else if (i < 212992) v = s3[i - 114688];
    else                 v = s4[i - 212992];
    W[i] = f2bf(v);
}

// ------ depthwise 3x3 -> bf16 k-interleaved Y [b][C/8][HW][8], strip/thread --
// Thread = 1 channel x 8-px horizontal strip (strips never cross rows).
// 3 vector row-loads + 6 halo scalars per 8 outputs; taps in reference order.
template <int C, int IMH, int IMW, typename TIN>
__global__ __launch_bounds__(256) void dw_kernel(const TIN* __restrict__ in,
                                                 const float* __restrict__ dww,
                                                 const float* __restrict__ dwb,
                                                 u16* __restrict__ Y) {
    constexpr int HW = IMH * IMW;
    constexpr int NSTRIP = HW / 8;
    const int strip = blockIdx.x * 32 + (threadIdx.x >> 3);
    if (strip >= NSTRIP) return;
    const int icq = threadIdx.x & 7;
    const int icg = blockIdx.y, b = blockIdx.z;
    const int ic  = icg * 8 + icq;
    const int px0 = strip * 8;
    const int h   = px0 / IMW, w0 = px0 % IMW;

    const TIN* ip = in + ((size_t)b * C + ic) * HW;
    float r[3][8], lh[3], rh[3];
#pragma unroll
    for (int dr = 0; dr < 3; dr++) {
        int hh = h + dr - 1;
        if (hh < 0 || hh >= IMH) {
#pragma unroll
            for (int j = 0; j < 8; j++) r[dr][j] = 0.f;
            lh[dr] = 0.f; rh[dr] = 0.f;
        } else {
            const TIN* rp = ip + hh * IMW + w0;
            if constexpr (sizeof(TIN) == 4) {
                float4 a = *(const float4*)rp;
                float4 c = *(const float4*)(rp + 4);
                r[dr][0] = a.x; r[dr][1] = a.y; r[dr][2] = a.z; r[dr][3] = a.w;
                r[dr][4] = c.x; r[dr][5] = c.y; r[dr][6] = c.z; r[dr][7] = c.w;
            } else {
                u16x8 a = *(const u16x8*)rp;
#pragma unroll
                for (int j = 0; j < 8; j++) r[dr][j] = bf2f(a[j]);
            }
            lh[dr] = (w0 > 0)           ? ldf(rp[-1]) : 0.f;
            rh[dr] = (w0 + 8 < IMW)     ? ldf(rp[8])  : 0.f;
        }
    }
    const float* wp = dww + ic * 9;
    float wv[9];
#pragma unroll
    for (int t = 0; t < 9; t++) wv[t] = wp[t];
    const float b0 = dwb[ic];

    u16* op = Y + (((size_t)b * (C / 8) + icg) * HW + px0) * 8 + icq;
#pragma unroll
    for (int j = 0; j < 8; j++) {
        float y = b0;
#pragma unroll
        for (int dr = 0; dr < 3; dr++) {
            float l = (j == 0) ? lh[dr] : r[dr][j - 1];
            float m = r[dr][j];
            float rr = (j == 7) ? rh[dr] : r[dr][j + 1];
            y = fmaf(wv[dr * 3 + 0], l, y);
            y = fmaf(wv[dr * 3 + 1], m, y);
            y = fmaf(wv[dr * 3 + 2], rr, y);
        }
        op[j * 8] = f2bf(y);
    }
}

// --------------- pointwise 1x1 as bf16 MFMA GEMM: out = W x Y + bias --------
// MODE 0: out[b][totc][M] (TOUT). MODE 1 (hqkv): window-major dual layout:
//   oc<256 (Q,K): qkout[((b*576+g)*16+q)*256 + oc]          (q-major)
//   oc>=256 (V):  vout[((b*576+g)*128 + oc-256)*16 + q]     (ch-major)
// MODE 1 epilogue restages acc through LDS so global stores are wide and
// line-coalesced (fix for 4.7x HBM write amplification of 2B scatter).
template <int IC, int M, typename TOUT, int MODE>
__global__ __launch_bounds__(256) void pw_gemm(const u16* __restrict__ Y,
                                               const u16* __restrict__ Wmat,
                                               const float* __restrict__ bias,
                                               TOUT* __restrict__ out,
                                               int totc, int ocoff,
                                               u16* __restrict__ qkout,
                                               u16* __restrict__ vout) {
    const int tid  = threadIdx.x;
    const int wave = tid >> 6, lane = tid & 63;
    const int col  = lane & 15, oct = lane >> 4;
    const int mw   = (wave & 1) * 64, nw = (wave >> 1) * 64;
    const int px0    = blockIdx.x * 128;
    const int octile = blockIdx.y;
    const int b      = blockIdx.z;

    __shared__ union {
        struct { u16 W[128 * 72]; u16 Y[8 * 128 * 8]; } g;   // 34816 B
        u16 stage[4][64 * 72];                               // 36864 B (MODE 1)
    } lds;
    u16* const Wlds = lds.g.W;      // [oc][64ic] rows padded 64->72
    u16* const Ylds = lds.g.Y;      // [icg][px][8]

    f32x4 acc[4][4];
    const f32x4 zero = {0.f, 0.f, 0.f, 0.f};
#pragma unroll
    for (int i = 0; i < 4; i++)
#pragma unroll
        for (int j = 0; j < 4; j++) acc[i][j] = zero;

    const u16* Yb = Y + (size_t)b * (IC / 8) * M * 8;

    for (int kc = 0; kc < IC; kc += 64) {
        __syncthreads();
#pragma unroll
        for (int i = 0; i < 4; i++) {              // stage W tile (16 KB)
            int c = tid + i * 256;
            int r = c >> 3, seg = c & 7;
            u16x8 v = *(const u16x8*)(Wmat + (size_t)(octile * 128 + r) * IC + kc + seg * 8);
            *(u16x8*)&Wlds[r * 72 + seg * 8] = v;
        }
#pragma unroll
        for (int i = 0; i < 4; i++) {              // stage Y tile (16 KB)
            int c = tid + i * 256;
            int ig = c >> 7, pl = c & 127;
            int px = px0 + pl; if (px > M - 1) px = M - 1;   // clamp partial tile
            u16x8 v = *(const u16x8*)(Yb + ((size_t)(kc / 8 + ig) * M + px) * 8);
            *(u16x8*)&Ylds[(ig * 128 + pl) * 8] = v;
        }
        __syncthreads();
#pragma unroll
        for (int kcs = 0; kcs < 2; kcs++) {
            bf16x8 Af[4], Bf[4];
#pragma unroll
            for (int mt = 0; mt < 4; mt++)         // A[m=oc][k=ic]
                Af[mt] = *(const bf16x8*)&Wlds[(mw + mt * 16 + col) * 72 + kcs * 32 + oct * 8];
#pragma unroll
            for (int nt = 0; nt < 4; nt++)         // B[k=ic][n=px]
                Bf[nt] = *(const bf16x8*)&Ylds[((kcs * 4 + oct) * 128 + nw + nt * 16 + col) * 8];
#pragma unroll
            for (int mt = 0; mt < 4; mt++)
#pragma unroll
                for (int nt = 0; nt < 4; nt++)
                    acc[mt][nt] = __builtin_amdgcn_mfma_f32_16x16x32_bf16(
                        Af[mt], Bf[nt], acc[mt][nt], 0, 0, 0);
        }
    }
    if constexpr (MODE == 1) {
        // ---- restage wave's 64(oc) x 64(px) tile to LDS as [px][oc] (pad 72)
        __syncthreads();                           // all waves done with W/Y LDS
        u16* const stg = lds.stage[wave];
#pragma unroll
        for (int mt = 0; mt < 4; mt++)
#pragma unroll
            for (int nt = 0; nt < 4; nt++) {
                u16x4 pk;
#pragma unroll
                for (int i = 0; i < 4; i++) {
                    int oc = octile * 128 + mw + mt * 16 + oct * 4 + i;
                    pk[i] = f2bf(acc[mt][nt][i] + bias[oc]);
                }
                *(u16x4*)&stg[(nt * 16 + col) * 72 + mt * 16 + oct * 4] = pk;
            }
        __syncthreads();
        if (octile < 2) {
            // QK: per (g,q) row the wave owns a contiguous 128B oc-chunk.
            // 4 lanes/px x u16x8 -> each store instr covers 16 full 64B lines.
            const int p4 = lane >> 2, piece = lane & 3;
#pragma unroll
            for (int pp = 0; pp < 4; pp++) {
                int pl = pp * 16 + p4;             // px_local 0..63
                int px = px0 + nw + pl;
                int h = px / 96, w = px - h * 96;
                int g = (h >> 2) * 24 + (w >> 2);
                int q = (h & 3) * 4 + (w & 3);
                size_t base = (((size_t)b * 576 + g) * 16 + q) * 256
                            + (size_t)(octile * 128 + mw);
#pragma unroll
                for (int half = 0; half < 2; half++) {
                    u16x8 v = *(const u16x8*)&stg[pl * 72 + half * 32 + piece * 8];
                    *(u16x8*)&qkout[base + half * 32 + piece * 8] = v;
                }
            }
        } else {
            // V (ch-major): pack the 4 consecutive q of a window row into one
            // 8B store; lanes sweep consecutive vc. Adjacent bx blocks supply
            // the other q-rows of the same lines (L2 merge).
#pragma unroll
            for (int it = 0; it < 16; it++) {
                int pl0 = it * 4;                  // 4-px run, same (g, qrow)
                int px = px0 + nw + pl0;
                int h = px / 96, w = px - h * 96;
                int g = (h >> 2) * 24 + (w >> 2);
                int qrow = h & 3;
                int vc = mw + lane;
                u16x4 pk;
#pragma unroll
                for (int j = 0; j < 4; j++) pk[j] = stg[(pl0 + j) * 72 + lane];
                *(u16x4*)&vout[(((size_t)b * 576 + g) * 128 + vc) * 16 + qrow * 4] = pk;
            }
        }
        return;
    }
    // MODE 0 epilogue: C row = oc (oct*4+i), col = px (lane&15)
#pragma unroll
    for (int mt = 0; mt < 4; mt++) {
#pragma unroll
        for (int i = 0; i < 4; i++) {
            int ocl = mw + mt * 16 + oct * 4 + i;
            int oc  = octile * 128 + ocl;
            float bv = bias[oc];
            TOUT* op = out + ((size_t)b * totc + ocoff + oc) * M;
#pragma unroll
            for (int nt = 0; nt < 4; nt++) {
                int px = px0 + nw + nt * 16 + col;
                if (px < M) {
                    float v = acc[mt][nt][i] + bv;
                    if constexpr (sizeof(TOUT) == 2) op[px] = (TOUT)f2bf(v);
                    else                             op[px] = v;
                }
            }
        }
    }
}

// ------------------- low (global) attention — bf16 MFMA, tiled --------------
// r8 inner loop (Plds round-trip softmax), 6 K/V phases of 96 keys.
// r10: block covers 128 q (qt=2), grid 72 qtiles -> 2304 blocks = 9/CU.
// LDS = 96*56*2 + 32*104*2 + 4*16*56*2 = 24576 B.
__global__ __launch_bounds__(256) void low_attn_mfma(const u16* __restrict__ lq,
                                                     const u16* __restrict__ lkv,
                                                     u16* __restrict__ o) {
    const int qtile = blockIdx.x, head = blockIdx.y, b = blockIdx.z;
    const int tid  = threadIdx.x;
    const int wave = tid >> 6, lane = tid & 63;
    const int col  = lane & 15, oct = lane >> 4;

    __shared__ u16 Klds[96][56];    // [k][d] transposed K, d padded 32->56
    __shared__ u16 Vlds[32][104];   // [d][k], k padded 96->104
    __shared__ u16 Plds[4][16][56];

    const size_t qb  = ((size_t)b * 128 + head * 32) * 9216;
    const size_t kb  = ((size_t)b * 256 + head * 32) * 576;
    const size_t vb  = kb + (size_t)128 * 576;
    const int    q0w = qtile * 128 + wave * 32;

    bf16x8 Qf[2];                                   // A[m=q][k=d]
#pragma unroll
    for (int qt = 0; qt < 2; qt++)
#pragma unroll
        for (int j = 0; j < 8; j++)
            Qf[qt][j] = (short)lq[qb + (size_t)(oct * 8 + j) * 9216 + q0w + qt * 16 + col];

    bf16x8 ones;
#pragma unroll
    for (int j = 0; j < 8; j++) ones[j] = (short)0x3F80;

    f32x4 Oacc[2][2], Lacc[2];
    const f32x4 zero = {0.f, 0.f, 0.f, 0.f};
#pragma unroll
    for (int qt = 0; qt < 2; qt++) {
        Oacc[qt][0] = zero; Oacc[qt][1] = zero; Lacc[qt] = zero;
    }

    for (int ph = 0; ph < 6; ph++) {
        __syncthreads();
        const int k0 = ph * 96;
#pragma unroll
        for (int i = 0; i < 3; i++) {               // stage K (transposed) + V
            int idx = tid + i * 256;                // 768 = 32d x 24 groups
            int d  = idx / 24;
            int kq = (idx % 24) * 4;
            u16x4 kv = *(const u16x4*)(lkv + kb + (size_t)d * 576 + k0 + kq);
            Klds[kq + 0][d] = kv.x;
            Klds[kq + 1][d] = kv.y;
            Klds[kq + 2][d] = kv.z;
            Klds[kq + 3][d] = kv.w;
            *(u16x4*)&Vlds[d][kq] = *(const u16x4*)(lkv + vb + (size_t)d * 576 + k0 + kq);
        }
        __syncthreads();

        for (int kc = 0; kc < 96; kc += 32) {
            bf16x8 Kf0 = *(const bf16x8*)&Klds[kc + col][oct * 8];
            bf16x8 Kf1 = *(const bf16x8*)&Klds[kc + 16 + col][oct * 8];
            bf16x8 Vf0 = *(const bf16x8*)&Vlds[col][kc + oct * 8];
            bf16x8 Vf1 = *(const bf16x8*)&Vlds[16 + col][kc + oct * 8];
#pragma unroll
            for (int qt = 0; qt < 2; qt++) {
                f32x4 S0 = __builtin_amdgcn_mfma_f32_16x16x32_bf16(Qf[qt], Kf0, zero, 0, 0, 0);
                f32x4 S1 = __builtin_amdgcn_mfma_f32_16x16x32_bf16(Qf[qt], Kf1, zero, 0, 0, 0);
#pragma unroll
                for (int i = 0; i < 4; i++) {       // SCALE folded into exp arg
                    Plds[wave][oct * 4 + i][col]      = f2bf(__expf(S0[i] * SCALE_F));
                    Plds[wave][oct * 4 + i][16 + col] = f2bf(__expf(S1[i] * SCALE_F));
                }
                bf16x8 Pf = *(const bf16x8*)&Plds[wave][col][oct * 8];
                Oacc[qt][0] = __builtin_amdgcn_mfma_f32_16x16x32_bf16(Pf, Vf0, Oacc[qt][0], 0, 0, 0);
                Oacc[qt][1] = __builtin_amdgcn_mfma_f32_16x16x32_bf16(Pf, Vf1, Oacc[qt][1], 0, 0, 0);
                Lacc[qt]    = __builtin_amdgcn_mfma_f32_16x16x32_bf16(Pf, ones, Lacc[qt], 0, 0, 0);
            }
        }
    }

#pragma unroll
    for (int qt = 0; qt < 2; qt++) {
        f32x4 rl;
#pragma unroll
        for (int i = 0; i < 4; i++) rl[i] = 1.f / Lacc[qt][i];
#pragma unroll
        for (int dh = 0; dh < 2; dh++)
#pragma unroll
            for (int i = 0; i < 4; i++)
                o[qb + (size_t)(dh * 16 + col) * 9216 + q0w + qt * 16 + oct * 4 + i] =
                    f2bf(Oacc[qt][dh][i] * rl[i]);
    }
}

// ----------- high (windowed 4x4) attention — MFMA, direct global ------------
__global__ __launch_bounds__(256) void high_attn_mfma(const u16* __restrict__ qk,
                                                      const u16* __restrict__ v,
                                                      u16* __restrict__ ho) {
    const int wave = threadIdx.x >> 6, lane = threadIdx.x & 63;
    const int col = lane & 15, oct = lane >> 4;
    const int gidx = blockIdx.x * 4 + wave;        // 0..4607
    const int b = gidx / 576, g = gidx % 576;

    __shared__ u16 Plds[4][16][36];                // per-wave, keys padded to 32
    for (int i = lane; i < 16 * 20; i += 64) {     // zero key cols 16..35 once
        Plds[wave][i / 20][16 + i % 20] = 0;
    }
    const u16* qkw = qk + (size_t)gidx * 16 * 256;
    const u16* vw  = v  + (size_t)gidx * 128 * 16;
    const int px0  = ((g / 24) * 4) * 96 + (g % 24) * 4;
    u16* ob = ho + (size_t)b * 128 * 9216 + px0;
    const int qy = col >> 2, qx = col & 3;

    const f32x4 zero = {0.f, 0.f, 0.f, 0.f};
    bf16x8 ones;
#pragma unroll
    for (int j = 0; j < 8; j++) ones[j] = (short)0x3F80;

#pragma unroll
    for (int hd = 0; hd < 4; hd++) {
        bf16x8 Qf = *(const bf16x8*)(qkw + col * 256 + hd * 32 + oct * 8);
        bf16x8 Kf = *(const bf16x8*)(qkw + col * 256 + 128 + hd * 32 + oct * 8);
        f32x4 S = __builtin_amdgcn_mfma_f32_16x16x32_bf16(Qf, Kf, zero, 0, 0, 0);
#pragma unroll
        for (int i = 0; i < 4; i++)                // S[q=oct*4+i][key=col]
            Plds[wave][oct * 4 + i][col] = f2bf(__expf(S[i] * SCALE_F));
        bf16x8 Pf = *(const bf16x8*)&Plds[wave][col][oct * 8];
        bf16x8 Vf0 = *(const bf16x8*)(vw + (hd * 32 + col) * 16 + oct * 8);
        bf16x8 Vf1 = *(const bf16x8*)(vw + (hd * 32 + 16 + col) * 16 + oct * 8);
        f32x4 O0 = __builtin_amdgcn_mfma_f32_16x16x32_bf16(Vf0, Pf, zero, 0, 0, 0);
        f32x4 O1 = __builtin_amdgcn_mfma_f32_16x16x32_bf16(Vf1, Pf, zero, 0, 0, 0);
        f32x4 Ld = __builtin_amdgcn_mfma_f32_16x16x32_bf16(ones, Pf, zero, 0, 0, 0);
        float rl = 1.f / Ld[0];                    // L[q=col] (any row)
#pragma unroll
        for (int i = 0; i < 4; i++) {              // O[d][q=col]
            ob[(size_t)(hd * 32 + oct * 4 + i) * 9216 + qy * 96 + qx]      = f2bf(O0[i] * rl);
            ob[(size_t)(hd * 32 + 16 + oct * 4 + i) * 9216 + qy * 96 + qx] = f2bf(O1[i] * rl);
        }
    }
}

// ---------------------------------------------------------------- launch ----
extern "C" void kernel_launch(void* const* d_in, const int* in_sizes, int n_in,
                              void* d_out, int out_size, void* d_ws, size_t ws_size,
                              hipStream_t stream) {
    const float* x         = (const float*)d_in[0];
    const float* restore_w = (const float*)d_in[1];
    const float* restore_b = (const float*)d_in[2];
    const float* lq_dw_w   = (const float*)d_in[3];
    const float* lq_dw_b   = (const float*)d_in[4];
    const float* lq_pw_w   = (const float*)d_in[5];
    const float* lq_pw_b   = (const float*)d_in[6];
    const float* lkv_dw_w  = (const float*)d_in[7];
    const float* lkv_dw_b  = (const float*)d_in[8];
    const float* lkv_pw_w  = (const float*)d_in[9];
    const float* lkv_pw_b  = (const float*)d_in[10];
    const float* lpr_dw_w  = (const float*)d_in[11];
    const float* lpr_dw_b  = (const float*)d_in[12];
    const float* lpr_pw_w  = (const float*)d_in[13];
    const float* lpr_pw_b  = (const float*)d_in[14];
    const float* hq_dw_w   = (const float*)d_in[15];
    const float* hq_dw_b   = (const float*)d_in[16];
    const float* hq_pw_w   = (const float*)d_in[17];
    const float* hq_pw_b   = (const float*)d_in[18];
    const float* hp_dw_w   = (const float*)d_in[19];
    const float* hp_dw_b   = (const float*)d_in[20];
    const float* hp_pw_w   = (const float*)d_in[21];
    const float* hp_pw_b   = (const float*)d_in[22];
    float* out = (float*)d_out;
    char*  wsb = (char*)d_ws;

    // -------- workspace layout (bytes); all overlays safe by stream order ----
    u16*   Wbf    = (u16*)  (wsb + 0);           //  0.46 MB
    float* low    = (float*)(wsb + 524288);      //  4.7 MB fp32
    u16*   highbf = (u16*)  (wsb + 5242880);     // 18.9 MB bf16
    u16*   ho     = (u16*)  (wsb + 5242880);     // reuse (high dead after dw hqkv)
    u16*   Yhproj = (u16*)  (wsb + 24117248);    // 18.9 MB
    u16*   Ylq    = (u16*)  (wsb + 80740352);    // 37.7 MB
    u16*   Yhqkv  = (u16*)  (wsb + 80740352);    // reuse Ylq
    u16*   lqbf   = (u16*)  (wsb + 118489088);   // 18.9 MB
    u16*   QKwin  = (u16*)  (wsb + 118489088);   // 37.7 MB (overlays dead lqbf/attnL)
    u16*   Vwin   = (u16*)  (wsb + 156237824);   // 18.9 MB (overlays dead attnL/Ylproj)
    u16*   Ylkv   = (u16*)  (wsb + 137363456);   //  2.4 MB
    u16*   lkvbf  = (u16*)  (wsb + 139722752);   //  2.4 MB
    u16*   attnL  = (u16*)  (wsb + 142082048);   // 18.9 MB
    u16*   Ylproj = (u16*)  (wsb + 160956416);   // 18.9 MB -> peak 179.8 MB

    const u16* wlq    = Wbf;
    const u16* wlkv   = Wbf + 32768;
    const u16* wlproj = Wbf + 98304;
    const u16* whqkv  = Wbf + 114688;
    const u16* whproj = Wbf + 212992;

    wcvt_kernel<<<896, 256, 0, stream>>>(lq_pw_w, lkv_pw_w, lpr_pw_w, hq_pw_w, hp_pw_w, Wbf);
    pool_kernel<<<4608, 256, 0, stream>>>(x, low);
    high_kernel<<<dim3(36, 4, 8), 256, 0, stream>>>(x, low, restore_w, restore_b, highbf);

    dw_kernel<256, 96, 96, float><<<dim3(36, 32, 8), 256, 0, stream>>>(x, lq_dw_w, lq_dw_b, Ylq);
    pw_gemm<256, 9216, u16, 0><<<dim3(72, 1, 8), 256, 0, stream>>>(
        Ylq, wlq, lq_pw_b, lqbf, 128, 0, nullptr, nullptr);

    dw_kernel<256, 24, 24, float><<<dim3(3, 32, 8), 256, 0, stream>>>(low, lkv_dw_w, lkv_dw_b, Ylkv);
    pw_gemm<256, 576, u16, 0><<<dim3(5, 2, 8), 256, 0, stream>>>(
        Ylkv, wlkv, lkv_pw_b, lkvbf, 256, 0, nullptr, nullptr);

    low_attn_mfma<<<dim3(72, 4, 8), 256, 0, stream>>>(lqbf, lkvbf, attnL);

    dw_kernel<128, 96, 96, u16><<<dim3(36, 16, 8), 256, 0, stream>>>(attnL, lpr_dw_w, lpr_dw_b, Ylproj);
    pw_gemm<128, 9216, float, 0><<<dim3(72, 1, 8), 256, 0, stream>>>(
        Ylproj, wlproj, lpr_pw_b, out, 256, 0, nullptr, nullptr);

    dw_kernel<256, 96, 96, u16><<<dim3(36, 32, 8), 256, 0, stream>>>(highbf, hq_dw_w, hq_dw_b, Yhqkv);
    pw_gemm<256, 9216, u16, 1><<<dim3(72, 3, 8), 256, 0, stream>>>(
        Yhqkv, whqkv, hq_pw_b, QKwin, 384, 0, QKwin, Vwin);

    high_attn_mfma<<<1152, 256, 0, stream>>>(QKwin, Vwin, ho);

    dw_kernel<128, 96, 96, u16><<<dim3(36, 16, 8), 256, 0, stream>>>(ho, hp_dw_w, hp_dw_b, Yhproj);
    pw_gemm<128, 9216, float, 0><<<dim3(72, 1, 8), 256, 0, stream>>>(
        Yhproj, whproj, hp_pw_b, out, 256, 128, nullptr, nullptr);
}

// Round 9
// 528.606 us; speedup vs baseline: 1.0376x; 1.0171x over previous
//
#include <hip/hip_runtime.h>

// HiLoAttention on MI355X — round 11: low_attn LDS-conflict + VALU fixes.
// (1) XOR d-block swizzle on Klds: store (k,d) at col d ^ ((k/4 & 3)<<3) —
//     kills the 12-24-way K-transpose write conflict; b128 reads stay
//     aligned and become conflict-free. (2) P conversion 5-op RNE -> 2-op
//     round-nearest (ties-away; P-only, self-normalizing). r10 grid kept.
// B=8, DIM=256, H=W=96, WS=4.

#define SCALE_F 0.17677669529663687f   // 32^-0.5

typedef unsigned short u16;
typedef __attribute__((ext_vector_type(8))) short bf16x8;
typedef __attribute__((ext_vector_type(4))) float f32x4;
typedef __attribute__((ext_vector_type(8))) u16 u16x8;
typedef __attribute__((ext_vector_type(4))) u16 u16x4;

static __device__ __forceinline__ u16 f2bf(float f) {
    unsigned u = __float_as_uint(f);
    return (u16)((u + 0x7FFF + ((u >> 16) & 1)) >> 16);   // RNE
}
static __device__ __forceinline__ u16 f2bf_rna(float f) {  // ties-away, 2 ops
    return (u16)((__float_as_uint(f) + 0x8000u) >> 16);
}
static __device__ __forceinline__ float bf2f(u16 v) {
    return __uint_as_float((unsigned)v << 16);
}
static __device__ __forceinline__ float ldf(float v) { return v; }
static __device__ __forceinline__ float ldf(u16 v)   { return bf2f(v); }

// ------------------------------------------------------------------ pool ----
__global__ __launch_bounds__(256) void pool_kernel(const float* __restrict__ x,
                                                   float* __restrict__ low) {
    int o = blockIdx.x * 256 + threadIdx.x;        // [b*256+c][hg][wg]
    int wg = o % 24;
    int t  = o / 24;
    int hg = t % 24;
    int bc = t / 24;
    const float* xp = x + (size_t)bc * 9216 + (hg * 4) * 96 + wg * 4;
    float s = 0.f;
#pragma unroll
    for (int r = 0; r < 4; r++) {
        float4 v = *(const float4*)(xp + r * 96);
        s += (v.x + v.y) + (v.z + v.w);
    }
    low[o] = s * (1.f / 16.f);
}

// ------------- high = restore(pixshuf(low)) - x, bf16 out, reg-reuse --------
__global__ __launch_bounds__(256) void high_kernel(const float* __restrict__ x,
                                                   const float* __restrict__ low,
                                                   const float* __restrict__ rw,
                                                   const float* __restrict__ rb,
                                                   u16* __restrict__ high) {
    int px = blockIdx.x * 256 + threadIdx.x;       // 0..9215
    int cg = blockIdx.y;                           // channel chunk (64 each)
    int b  = blockIdx.z;
    int h = px / 96, w = px % 96;
    int sub = (h & 3) * 4 + (w & 3);               // pixel-shuffle sub-channel
    const float* lp = low + ((size_t)b * 256 + sub) * 576 + (h >> 2) * 24 + (w >> 2);
    float lv[16];
#pragma unroll
    for (int co = 0; co < 16; co++) lv[co] = lp[(size_t)co * 16 * 576];
    const float* xp = x    + ((size_t)b * 256 + cg * 64) * 9216 + px;
    u16*         hp = high + ((size_t)b * 256 + cg * 64) * 9216 + px;
#pragma unroll 4
    for (int cl = 0; cl < 64; cl++) {
        int c = cg * 64 + cl;                      // uniform -> rw/rb scalar loads
        float a = rb[c] - xp[(size_t)cl * 9216];
#pragma unroll
        for (int co = 0; co < 16; co++)
            a = fmaf(rw[c * 16 + co], lv[co], a);
        hp[(size_t)cl * 9216] = f2bf(a);
    }
}

// ------------------------- pw-weight fp32 -> bf16 conversion ----------------
__global__ __launch_bounds__(256) void wcvt_kernel(const float* __restrict__ s0,
                                                   const float* __restrict__ s1,
                                                   const float* __restrict__ s2,
                                                   const float* __restrict__ s3,
                                                   const float* __restrict__ s4,
                                                   u16* __restrict__ W) {
    int i = blockIdx.x * 256 + threadIdx.x;        // 229376 total
    float v;
    if      (i < 32768)  v = s0[i];
    else if (i < 98304)  v = s1[i - 32768];
    else if (i < 114688) v = s2[i - 98304];
    else if (i < 212992) v = s3[i - 114688];
    else                 v = s4[i - 212992];
    W[i] = f2bf(v);
}

// ------ depthwise 3x3 -> bf16 k-interleaved Y [b][C/8][HW][8], strip/thread --
// Thread = 1 channel x 8-px horizontal strip (strips never cross rows).
// 3 vector row-loads + 6 halo scalars per 8 outputs; taps in reference order.
template <int C, int IMH, int IMW, typename TIN>
__global__ __launch_bounds__(256) void dw_kernel(const TIN* __restrict__ in,
                                                 const float* __restrict__ dww,
                                                 const float* __restrict__ dwb,
                                                 u16* __restrict__ Y) {
    constexpr int HW = IMH * IMW;
    constexpr int NSTRIP = HW / 8;
    const int strip = blockIdx.x * 32 + (threadIdx.x >> 3);
    if (strip >= NSTRIP) return;
    const int icq = threadIdx.x & 7;
    const int icg = blockIdx.y, b = blockIdx.z;
    const int ic  = icg * 8 + icq;
    const int px0 = strip * 8;
    const int h   = px0 / IMW, w0 = px0 % IMW;

    const TIN* ip = in + ((size_t)b * C + ic) * HW;
    float r[3][8], lh[3], rh[3];
#pragma unroll
    for (int dr = 0; dr < 3; dr++) {
        int hh = h + dr - 1;
        if (hh < 0 || hh >= IMH) {
#pragma unroll
            for (int j = 0; j < 8; j++) r[dr][j] = 0.f;
            lh[dr] = 0.f; rh[dr] = 0.f;
        } else {
            const TIN* rp = ip + hh * IMW + w0;
            if constexpr (sizeof(TIN) == 4) {
                float4 a = *(const float4*)rp;
                float4 c = *(const float4*)(rp + 4);
                r[dr][0] = a.x; r[dr][1] = a.y; r[dr][2] = a.z; r[dr][3] = a.w;
                r[dr][4] = c.x; r[dr][5] = c.y; r[dr][6] = c.z; r[dr][7] = c.w;
            } else {
                u16x8 a = *(const u16x8*)rp;
#pragma unroll
                for (int j = 0; j < 8; j++) r[dr][j] = bf2f(a[j]);
            }
            lh[dr] = (w0 > 0)           ? ldf(rp[-1]) : 0.f;
            rh[dr] = (w0 + 8 < IMW)     ? ldf(rp[8])  : 0.f;
        }
    }
    const float* wp = dww + ic * 9;
    float wv[9];
#pragma unroll
    for (int t = 0; t < 9; t++) wv[t] = wp[t];
    const float b0 = dwb[ic];

    u16* op = Y + (((size_t)b * (C / 8) + icg) * HW + px0) * 8 + icq;
#pragma unroll
    for (int j = 0; j < 8; j++) {
        float y = b0;
#pragma unroll
        for (int dr = 0; dr < 3; dr++) {
            float l = (j == 0) ? lh[dr] : r[dr][j - 1];
            float m = r[dr][j];
            float rr = (j == 7) ? rh[dr] : r[dr][j + 1];
            y = fmaf(wv[dr * 3 + 0], l, y);
            y = fmaf(wv[dr * 3 + 1], m, y);
            y = fmaf(wv[dr * 3 + 2], rr, y);
        }
        op[j * 8] = f2bf(y);
    }
}

// --------------- pointwise 1x1 as bf16 MFMA GEMM: out = W x Y + bias --------
// MODE 0: out[b][totc][M] (TOUT). MODE 1 (hqkv): window-major dual layout:
//   oc<256 (Q,K): qkout[((b*576+g)*16+q)*256 + oc]          (q-major)
//   oc>=256 (V):  vout[((b*576+g)*128 + oc-256)*16 + q]     (ch-major)
// MODE 1 epilogue restages acc through LDS so global stores are wide and
// line-coalesced (fix for 4.7x HBM write amplification of 2B scatter).
template <int IC, int M, typename TOUT, int MODE>
__global__ __launch_bounds__(256) void pw_gemm(const u16* __restrict__ Y,
                                               const u16* __restrict__ Wmat,
                                               const float* __restrict__ bias,
                                               TOUT* __restrict__ out,
                                               int totc, int ocoff,
                                               u16* __restrict__ qkout,
                                               u16* __restrict__ vout) {
    const int tid  = threadIdx.x;
    const int wave = tid >> 6, lane = tid & 63;
    const int col  = lane & 15, oct = lane >> 4;
    const int mw   = (wave & 1) * 64, nw = (wave >> 1) * 64;
    const int px0    = blockIdx.x * 128;
    const int octile = blockIdx.y;
    const int b      = blockIdx.z;

    __shared__ union {
        struct { u16 W[128 * 72]; u16 Y[8 * 128 * 8]; } g;   // 34816 B
        u16 stage[4][64 * 72];                               // 36864 B (MODE 1)
    } lds;
    u16* const Wlds = lds.g.W;      // [oc][64ic] rows padded 64->72
    u16* const Ylds = lds.g.Y;      // [icg][px][8]

    f32x4 acc[4][4];
    const f32x4 zero = {0.f, 0.f, 0.f, 0.f};
#pragma unroll
    for (int i = 0; i < 4; i++)
#pragma unroll
        for (int j = 0; j < 4; j++) acc[i][j] = zero;

    const u16* Yb = Y + (size_t)b * (IC / 8) * M * 8;

    for (int kc = 0; kc < IC; kc += 64) {
        __syncthreads();
#pragma unroll
        for (int i = 0; i < 4; i++) {              // stage W tile (16 KB)
            int c = tid + i * 256;
            int r = c >> 3, seg = c & 7;
            u16x8 v = *(const u16x8*)(Wmat + (size_t)(octile * 128 + r) * IC + kc + seg * 8);
            *(u16x8*)&Wlds[r * 72 + seg * 8] = v;
        }
#pragma unroll
        for (int i = 0; i < 4; i++) {              // stage Y tile (16 KB)
            int c = tid + i * 256;
            int ig = c >> 7, pl = c & 127;
            int px = px0 + pl; if (px > M - 1) px = M - 1;   // clamp partial tile
            u16x8 v = *(const u16x8*)(Yb + ((size_t)(kc / 8 + ig) * M + px) * 8);
            *(u16x8*)&Ylds[(ig * 128 + pl) * 8] = v;
        }
        __syncthreads();
#pragma unroll
        for (int kcs = 0; kcs < 2; kcs++) {
            bf16x8 Af[4], Bf[4];
#pragma unroll
            for (int mt = 0; mt < 4; mt++)         // A[m=oc][k=ic]
                Af[mt] = *(const bf16x8*)&Wlds[(mw + mt * 16 + col) * 72 + kcs * 32 + oct * 8];
#pragma unroll
            for (int nt = 0; nt < 4; nt++)         // B[k=ic][n=px]
                Bf[nt] = *(const bf16x8*)&Ylds[((kcs * 4 + oct) * 128 + nw + nt * 16 + col) * 8];
#pragma unroll
            for (int mt = 0; mt < 4; mt++)
#pragma unroll
                for (int nt = 0; nt < 4; nt++)
                    acc[mt][nt] = __builtin_amdgcn_mfma_f32_16x16x32_bf16(
                        Af[mt], Bf[nt], acc[mt][nt], 0, 0, 0);
        }
    }
    if constexpr (MODE == 1) {
        // ---- restage wave's 64(oc) x 64(px) tile to LDS as [px][oc] (pad 72)
        __syncthreads();                           // all waves done with W/Y LDS
        u16* const stg = lds.stage[wave];
#pragma unroll
        for (int mt = 0; mt < 4; mt++)
#pragma unroll
            for (int nt = 0; nt < 4; nt++) {
                u16x4 pk;
#pragma unroll
                for (int i = 0; i < 4; i++) {
                    int oc = octile * 128 + mw + mt * 16 + oct * 4 + i;
                    pk[i] = f2bf(acc[mt][nt][i] + bias[oc]);
                }
                *(u16x4*)&stg[(nt * 16 + col) * 72 + mt * 16 + oct * 4] = pk;
            }
        __syncthreads();
        if (octile < 2) {
            // QK: per (g,q) row the wave owns a contiguous 128B oc-chunk.
            // 4 lanes/px x u16x8 -> each store instr covers 16 full 64B lines.
            const int p4 = lane >> 2, piece = lane & 3;
#pragma unroll
            for (int pp = 0; pp < 4; pp++) {
                int pl = pp * 16 + p4;             // px_local 0..63
                int px = px0 + nw + pl;
                int h = px / 96, w = px - h * 96;
                int g = (h >> 2) * 24 + (w >> 2);
                int q = (h & 3) * 4 + (w & 3);
                size_t base = (((size_t)b * 576 + g) * 16 + q) * 256
                            + (size_t)(octile * 128 + mw);
#pragma unroll
                for (int half = 0; half < 2; half++) {
                    u16x8 v = *(const u16x8*)&stg[pl * 72 + half * 32 + piece * 8];
                    *(u16x8*)&qkout[base + half * 32 + piece * 8] = v;
                }
            }
        } else {
            // V (ch-major): pack the 4 consecutive q of a window row into one
            // 8B store; lanes sweep consecutive vc. Adjacent bx blocks supply
            // the other q-rows of the same lines (L2 merge).
#pragma unroll
            for (int it = 0; it < 16; it++) {
                int pl0 = it * 4;                  // 4-px run, same (g, qrow)
                int px = px0 + nw + pl0;
                int h = px / 96, w = px - h * 96;
                int g = (h >> 2) * 24 + (w >> 2);
                int qrow = h & 3;
                int vc = mw + lane;
                u16x4 pk;
#pragma unroll
                for (int j = 0; j < 4; j++) pk[j] = stg[(pl0 + j) * 72 + lane];
                *(u16x4*)&vout[(((size_t)b * 576 + g) * 128 + vc) * 16 + qrow * 4] = pk;
            }
        }
        return;
    }
    // MODE 0 epilogue: C row = oc (oct*4+i), col = px (lane&15)
#pragma unroll
    for (int mt = 0; mt < 4; mt++) {
#pragma unroll
        for (int i = 0; i < 4; i++) {
            int ocl = mw + mt * 16 + oct * 4 + i;
            int oc  = octile * 128 + ocl;
            float bv = bias[oc];
            TOUT* op = out + ((size_t)b * totc + ocoff + oc) * M;
#pragma unroll
            for (int nt = 0; nt < 4; nt++) {
                int px = px0 + nw + nt * 16 + col;
                if (px < M) {
                    float v = acc[mt][nt][i] + bv;
                    if constexpr (sizeof(TOUT) == 2) op[px] = (TOUT)f2bf(v);
                    else                             op[px] = v;
                }
            }
        }
    }
}

// ------------------- low (global) attention — bf16 MFMA, tiled --------------
// 6 K/V phases of 96 keys; block covers 128 q (qt=2), 2304 blocks.
// Klds XOR d-block swizzle: element (k,d) stored at column
// d ^ ((k/4 & 3)<<3) — bijective within the 32-wide row, constant per
// staging thread ((skq>>2)&3) and per reading lane ((col>>2)&3, since
// kc = 0/32/64 and the +16 tile don't change (k>>2)&3). Writes spread
// over 4 banks (was 2); b128 reads become conflict-free and stay 16B-aligned.
// LDS = 96*56*2 + 32*104*2 + 4*16*56*2 = 24576 B.
__global__ __launch_bounds__(256) void low_attn_mfma(const u16* __restrict__ lq,
                                                     const u16* __restrict__ lkv,
                                                     u16* __restrict__ o) {
    const int qtile = blockIdx.x, head = blockIdx.y, b = blockIdx.z;
    const int tid  = threadIdx.x;
    const int wave = tid >> 6, lane = tid & 63;
    const int col  = lane & 15, oct = lane >> 4;

    __shared__ u16 Klds[96][56];    // [k][swz(d)] transposed K, d padded 32->56
    __shared__ u16 Vlds[32][104];   // [d][k], k padded 96->104
    __shared__ u16 Plds[4][16][56];

    const size_t qb  = ((size_t)b * 128 + head * 32) * 9216;
    const size_t kb  = ((size_t)b * 256 + head * 32) * 576;
    const size_t vb  = kb + (size_t)128 * 576;
    const int    q0w = qtile * 128 + wave * 32;

    bf16x8 Qf[2];                                   // A[m=q][k=d]
#pragma unroll
    for (int qt = 0; qt < 2; qt++)
#pragma unroll
        for (int j = 0; j < 8; j++)
            Qf[qt][j] = (short)lq[qb + (size_t)(oct * 8 + j) * 9216 + q0w + qt * 16 + col];

    bf16x8 ones;
#pragma unroll
    for (int j = 0; j < 8; j++) ones[j] = (short)0x3F80;

    f32x4 Oacc[2][2], Lacc[2];
    const f32x4 zero = {0.f, 0.f, 0.f, 0.f};
#pragma unroll
    for (int qt = 0; qt < 2; qt++) {
        Oacc[qt][0] = zero; Oacc[qt][1] = zero; Lacc[qt] = zero;
    }

    const int kswz = ((col >> 2) & 3) << 3;         // read-side d-block XOR
    const int kcol0 = (oct * 8) ^ kswz;

    for (int ph = 0; ph < 6; ph++) {
        __syncthreads();
        const int k0 = ph * 96;
#pragma unroll
        for (int i = 0; i < 3; i++) {               // stage K (transposed) + V
            int idx = tid + i * 256;                // 768 = 32d x 24 groups
            int d  = idx / 24;
            int kq = (idx % 24) * 4;
            int cc = d ^ (((kq >> 2) & 3) << 3);    // write-side XOR (same 4 rows)
            u16x4 kv = *(const u16x4*)(lkv + kb + (size_t)d * 576 + k0 + kq);
            Klds[kq + 0][cc] = kv.x;
            Klds[kq + 1][cc] = kv.y;
            Klds[kq + 2][cc] = kv.z;
            Klds[kq + 3][cc] = kv.w;
            *(u16x4*)&Vlds[d][kq] = *(const u16x4*)(lkv + vb + (size_t)d * 576 + k0 + kq);
        }
        __syncthreads();

        for (int kc = 0; kc < 96; kc += 32) {
            bf16x8 Kf0 = *(const bf16x8*)&Klds[kc + col][kcol0];
            bf16x8 Kf1 = *(const bf16x8*)&Klds[kc + 16 + col][kcol0];
            bf16x8 Vf0 = *(const bf16x8*)&Vlds[col][kc + oct * 8];
            bf16x8 Vf1 = *(const bf16x8*)&Vlds[16 + col][kc + oct * 8];
#pragma unroll
            for (int qt = 0; qt < 2; qt++) {
                f32x4 S0 = __builtin_amdgcn_mfma_f32_16x16x32_bf16(Qf[qt], Kf0, zero, 0, 0, 0);
                f32x4 S1 = __builtin_amdgcn_mfma_f32_16x16x32_bf16(Qf[qt], Kf1, zero, 0, 0, 0);
#pragma unroll
                for (int i = 0; i < 4; i++) {       // SCALE folded into exp arg
                    Plds[wave][oct * 4 + i][col]      = f2bf_rna(__expf(S0[i] * SCALE_F));
                    Plds[wave][oct * 4 + i][16 + col] = f2bf_rna(__expf(S1[i] * SCALE_F));
                }
                bf16x8 Pf = *(const bf16x8*)&Plds[wave][col][oct * 8];
                Oacc[qt][0] = __builtin_amdgcn_mfma_f32_16x16x32_bf16(Pf, Vf0, Oacc[qt][0], 0, 0, 0);
                Oacc[qt][1] = __builtin_amdgcn_mfma_f32_16x16x32_bf16(Pf, Vf1, Oacc[qt][1], 0, 0, 0);
                Lacc[qt]    = __builtin_amdgcn_mfma_f32_16x16x32_bf16(Pf, ones, Lacc[qt], 0, 0, 0);
            }
        }
    }

#pragma unroll
    for (int qt = 0; qt < 2; qt++) {
        f32x4 rl;
#pragma unroll
        for (int i = 0; i < 4; i++) rl[i] = 1.f / Lacc[qt][i];
#pragma unroll
        for (int dh = 0; dh < 2; dh++)
#pragma unroll
            for (int i = 0; i < 4; i++)
                o[qb + (size_t)(dh * 16 + col) * 9216 + q0w + qt * 16 + oct * 4 + i] =
                    f2bf(Oacc[qt][dh][i] * rl[i]);
    }
}

// ----------- high (windowed 4x4) attention — MFMA, direct global ------------
__global__ __launch_bounds__(256) void high_attn_mfma(const u16* __restrict__ qk,
                                                      const u16* __restrict__ v,
                                                      u16* __restrict__ ho) {
    const int wave = threadIdx.x >> 6, lane = threadIdx.x & 63;
    const int col = lane & 15, oct = lane >> 4;
    const int gidx = blockIdx.x * 4 + wave;        // 0..4607
    const int b = gidx / 576, g = gidx % 576;

    __shared__ u16 Plds[4][16][36];                // per-wave, keys padded to 32
    for (int i = lane; i < 16 * 20; i += 64) {     // zero key cols 16..35 once
        Plds[wave][i / 20][16 + i % 20] = 0;
    }
    const u16* qkw = qk + (size_t)gidx * 16 * 256;
    const u16* vw  = v  + (size_t)gidx * 128 * 16;
    const int px0  = ((g / 24) * 4) * 96 + (g % 24) * 4;
    u16* ob = ho + (size_t)b * 128 * 9216 + px0;
    const int qy = col >> 2, qx = col & 3;

    const f32x4 zero = {0.f, 0.f, 0.f, 0.f};
    bf16x8 ones;
#pragma unroll
    for (int j = 0; j < 8; j++) ones[j] = (short)0x3F80;

#pragma unroll
    for (int hd = 0; hd < 4; hd++) {
        bf16x8 Qf = *(const bf16x8*)(qkw + col * 256 + hd * 32 + oct * 8);
        bf16x8 Kf = *(const bf16x8*)(qkw + col * 256 + 128 + hd * 32 + oct * 8);
        f32x4 S = __builtin_amdgcn_mfma_f32_16x16x32_bf16(Qf, Kf, zero, 0, 0, 0);
#pragma unroll
        for (int i = 0; i < 4; i++)                // S[q=oct*4+i][key=col]
            Plds[wave][oct * 4 + i][col] = f2bf(__expf(S[i] * SCALE_F));
        bf16x8 Pf = *(const bf16x8*)&Plds[wave][col][oct * 8];
        bf16x8 Vf0 = *(const bf16x8*)(vw + (hd * 32 + col) * 16 + oct * 8);
        bf16x8 Vf1 = *(const bf16x8*)(vw + (hd * 32 + 16 + col) * 16 + oct * 8);
        f32x4 O0 = __builtin_amdgcn_mfma_f32_16x16x32_bf16(Vf0, Pf, zero, 0, 0, 0);
        f32x4 O1 = __builtin_amdgcn_mfma_f32_16x16x32_bf16(Vf1, Pf, zero, 0, 0, 0);
        f32x4 Ld = __builtin_amdgcn_mfma_f32_16x16x32_bf16(ones, Pf, zero, 0, 0, 0);
        float rl = 1.f / Ld[0];                    // L[q=col] (any row)
#pragma unroll
        for (int i = 0; i < 4; i++) {              // O[d][q=col]
            ob[(size_t)(hd * 32 + oct * 4 + i) * 9216 + qy * 96 + qx]      = f2bf(O0[i] * rl);
            ob[(size_t)(hd * 32 + 16 + oct * 4 + i) * 9216 + qy * 96 + qx] = f2bf(O1[i] * rl);
        }
    }
}

// ---------------------------------------------------------------- launch ----
extern "C" void kernel_launch(void* const* d_in, const int* in_sizes, int n_in,
                              void* d_out, int out_size, void* d_ws, size_t ws_size,
                              hipStream_t stream) {
    const float* x         = (const float*)d_in[0];
    const float* restore_w = (const float*)d_in[1];
    const float* restore_b = (const float*)d_in[2];
    const float* lq_dw_w   = (const float*)d_in[3];
    const float* lq_dw_b   = (const float*)d_in[4];
    const float* lq_pw_w   = (const float*)d_in[5];
    const float* lq_pw_b   = (const float*)d_in[6];
    const float* lkv_dw_w  = (const float*)d_in[7];
    const float* lkv_dw_b  = (const float*)d_in[8];
    const float* lkv_pw_w  = (const float*)d_in[9];
    const float* lkv_pw_b  = (const float*)d_in[10];
    const float* lpr_dw_w  = (const float*)d_in[11];
    const float* lpr_dw_b  = (const float*)d_in[12];
    const float* lpr_pw_w  = (const float*)d_in[13];
    const float* lpr_pw_b  = (const float*)d_in[14];
    const float* hq_dw_w   = (const float*)d_in[15];
    const float* hq_dw_b   = (const float*)d_in[16];
    const float* hq_pw_w   = (const float*)d_in[17];
    const float* hq_pw_b   = (const float*)d_in[18];
    const float* hp_dw_w   = (const float*)d_in[19];
    const float* hp_dw_b   = (const float*)d_in[20];
    const float* hp_pw_w   = (const float*)d_in[21];
    const float* hp_pw_b   = (const float*)d_in[22];
    float* out = (float*)d_out;
    char*  wsb = (char*)d_ws;

    // -------- workspace layout (bytes); all overlays safe by stream order ----
    u16*   Wbf    = (u16*)  (wsb + 0);           //  0.46 MB
    float* low    = (float*)(wsb + 524288);      //  4.7 MB fp32
    u16*   highbf = (u16*)  (wsb + 5242880);     // 18.9 MB bf16
    u16*   ho     = (u16*)  (wsb + 5242880);     // reuse (high dead after dw hqkv)
    u16*   Yhproj = (u16*)  (wsb + 24117248);    // 18.9 MB
    u16*   Ylq    = (u16*)  (wsb + 80740352);    // 37.7 MB
    u16*   Yhqkv  = (u16*)  (wsb + 80740352);    // reuse Ylq
    u16*   lqbf   = (u16*)  (wsb + 118489088);   // 18.9 MB
    u16*   QKwin  = (u16*)  (wsb + 118489088);   // 37.7 MB (overlays dead lqbf/attnL)
    u16*   Vwin   = (u16*)  (wsb + 156237824);   // 18.9 MB (overlays dead attnL/Ylproj)
    u16*   Ylkv   = (u16*)  (wsb + 137363456);   //  2.4 MB
    u16*   lkvbf  = (u16*)  (wsb + 139722752);   //  2.4 MB
    u16*   attnL  = (u16*)  (wsb + 142082048);   // 18.9 MB
    u16*   Ylproj = (u16*)  (wsb + 160956416);   // 18.9 MB -> peak 179.8 MB

    const u16* wlq    = Wbf;
    const u16* wlkv   = Wbf + 32768;
    const u16* wlproj = Wbf + 98304;
    const u16* whqkv  = Wbf + 114688;
    const u16* whproj = Wbf + 212992;

    wcvt_kernel<<<896, 256, 0, stream>>>(lq_pw_w, lkv_pw_w, lpr_pw_w, hq_pw_w, hp_pw_w, Wbf);
    pool_kernel<<<4608, 256, 0, stream>>>(x, low);
    high_kernel<<<dim3(36, 4, 8), 256, 0, stream>>>(x, low, restore_w, restore_b, highbf);

    dw_kernel<256, 96, 96, float><<<dim3(36, 32, 8), 256, 0, stream>>>(x, lq_dw_w, lq_dw_b, Ylq);
    pw_gemm<256, 9216, u16, 0><<<dim3(72, 1, 8), 256, 0, stream>>>(
        Ylq, wlq, lq_pw_b, lqbf, 128, 0, nullptr, nullptr);

    dw_kernel<256, 24, 24, float><<<dim3(3, 32, 8), 256, 0, stream>>>(low, lkv_dw_w, lkv_dw_b, Ylkv);
    pw_gemm<256, 576, u16, 0><<<dim3(5, 2, 8), 256, 0, stream>>>(
        Ylkv, wlkv, lkv_pw_b, lkvbf, 256, 0, nullptr, nullptr);

    low_attn_mfma<<<dim3(72, 4, 8), 256, 0, stream>>>(lqbf, lkvbf, attnL);

    dw_kernel<128, 96, 96, u16><<<dim3(36, 16, 8), 256, 0, stream>>>(attnL, lpr_dw_w, lpr_dw_b, Ylproj);
    pw_gemm<128, 9216, float, 0><<<dim3(72, 1, 8), 256, 0, stream>>>(
        Ylproj, wlproj, lpr_pw_b, out, 256, 0, nullptr, nullptr);

    dw_kernel<256, 96, 96, u16><<<dim3(36, 32, 8), 256, 0, stream>>>(highbf, hq_dw_w, hq_dw_b, Yhqkv);
    pw_gemm<256, 9216, u16, 1><<<dim3(72, 3, 8), 256, 0, stream>>>(
        Yhqkv, whqkv, hq_pw_b, QKwin, 384, 0, QKwin, Vwin);

    high_attn_mfma<<<1152, 256, 0, stream>>>(QKwin, Vwin, ho);

    dw_kernel<128, 96, 96, u16><<<dim3(36, 16, 8), 256, 0, stream>>>(ho, hp_dw_w, hp_dw_b, Yhproj);
    pw_gemm<128, 9216, float, 0><<<dim3(72, 1, 8), 256, 0, stream>>>(
        Yhproj, whproj, hp_pw_b, out, 256, 128, nullptr, nullptr);
}